// Round 9
// baseline (230.577 us; speedup 1.0000x reference)
//
#include <hip/hip_runtime.h>
#include <hip/hip_bf16.h>

#define BB 16
#define DDIM 256
#define TLEN 4096
#define KCODES 1024
#define NQ (BB*TLEN)   // 65536
#define QB 64          // queries per k_mdist block
#define MAXC 32

#define FLT_MAX_C 3.402823466e+38f

using short8 = __attribute__((ext_vector_type(8))) short;
using f32x4  = __attribute__((ext_vector_type(4))) float;

// RNE fp32 -> bf16 (bit pattern), and back
__device__ __forceinline__ unsigned short f2bf(float x) {
  unsigned u = __float_as_uint(x);
  unsigned r = (u + 0x7fffu + ((u >> 16) & 1u)) >> 16;
  return (unsigned short)r;
}
__device__ __forceinline__ float bf2f(unsigned short h) {
  return __uint_as_float(((unsigned)h) << 16);
}

// ---------------------------------------------------------------------------
// numpy pairwise sum-of-squares over 256 elements (stride in elements).
// ---------------------------------------------------------------------------
__device__ __forceinline__ float np_sumsq_256(const float* p, int stride) {
  float th[2];
#pragma unroll
  for (int h = 0; h < 2; ++h) {
    const float* q = p + (size_t)h * 128 * (size_t)stride;
    float r[8];
#pragma unroll
    for (int j = 0; j < 8; ++j) {
      float v = q[(size_t)j * (size_t)stride];
      r[j] = __fmul_rn(v, v);
    }
    for (int i = 8; i < 128; i += 8) {
#pragma unroll
      for (int j = 0; j < 8; ++j) {
        float v = q[(size_t)(i + j) * (size_t)stride];
        r[j] = __fadd_rn(r[j], __fmul_rn(v, v));
      }
    }
    th[h] = __fadd_rn(__fadd_rn(__fadd_rn(r[0], r[1]), __fadd_rn(r[2], r[3])),
                      __fadd_rn(__fadd_rn(r[4], r[5]), __fadd_rn(r[6], r[7])));
  }
  return __fadd_rn(th[0], th[1]);
}

// ---------------------------------------------------------------------------
// k_prep: embT (for gather), e2 exact, bf16-hi split of emb [k][d],
// maxe = max|e| over all entries (rigorous bound input for the filter).
// ---------------------------------------------------------------------------
__global__ void k_prep(const float* __restrict__ emb, float* __restrict__ embT,
                       float* __restrict__ e2, short* __restrict__ ebh,
                       unsigned* __restrict__ maxe) {
  const int k = blockIdx.x;
  const int d = threadIdx.x;
  __shared__ float row[DDIM];
  float v = emb[(size_t)k * DDIM + d];
  row[d] = v;
  embT[(size_t)d * KCODES + k] = v;
  ebh[(size_t)k * DDIM + d] = (short)f2bf(v);
  float a = fabsf(v);
#pragma unroll
  for (int m = 1; m < 64; m <<= 1) a = fmaxf(a, __shfl_xor(a, m, 64));
  if ((threadIdx.x & 63) == 0) atomicMax(maxe, __float_as_uint(a));
  __syncthreads();
  if (d == 0) e2[k] = np_sumsq_256(row, 1);
}

// ---------------------------------------------------------------------------
// k_mdist v5: 512 threads = 8 waves; block = 64 queries x 1024 codes.
// ONE MFMA pass (zh*eh). Wave w owns codes [w*128,(w+1)*128), all 64 q.
// B (bh, 512KB/block) streams from L2 with 2-deep register prefetch; each
// 16B/lane load feeds 4 MFMAs. A-frags prebuilt once into LDS.
// Per-query rigorous candidate window: DELTA_q = 0.009*maxe*sabs_q + 2e-4
// (covers bf16 rounding of A and B, fp32 MFMA accum, and the reference's
// own z2+e2/2dot rounding slack, with ~2x margin). Exact fp32 recheck of
// candidates (reference rounding chain, z from LDS) -> bit-exact argmin.
// LDS 96KB: zf fp32 [256][64] (64KB) + abh [8ks][4mt][64lane] (32KB,
// epilogue arrays alias into it after the MFMA loop). 1 block/CU.
// ---------------------------------------------------------------------------
__global__ __launch_bounds__(512, 1)
void k_mdist(const float* __restrict__ z, const float* __restrict__ emb,
             const short* __restrict__ ebh, const float* __restrict__ e2,
             const unsigned* __restrict__ maxeU, int* __restrict__ idx,
             int* __restrict__ hist, double* __restrict__ lossp) {
  extern __shared__ __align__(16) char sbuf[];   // 98304 bytes
  float*  zf  = (float*)sbuf;                    // [256][64] exact z tile
  short8* abh = (short8*)(sbuf + 65536);         // [8ks][4mt][64lane]
  // epilogue aliases into the abh region (dead after MFMA loop):
  float* z2s  = (float*)(sbuf + 65536);          // [64]
  float* sabs = (float*)(sbuf + 65536 + 256);    // [64]
  float* sm   = (float*)(sbuf + 65536 + 512);    // [8][64]
  float* qmin = (float*)(sbuf + 65536 + 2560);   // [64]
  int*   cnt  = (int*)(sbuf + 65536 + 2816);     // [64]
  int*   ovf  = (int*)(sbuf + 65536 + 3072);     // [64]
  int*   cand = (int*)(sbuf + 65536 + 3328);     // [64][MAXC]
  float* bd   = (float*)(sbuf + 65536 + 11520);  // [64][8]
  int*   bk   = (int*)(sbuf + 65536 + 13568);    // [64][8]

  const int tid = threadIdx.x;
  const int lane = tid & 63;
  const int w = tid >> 6;   // 0..7
  const int g = lane >> 4;  // 0..3
  const int c = lane & 15;
  const int n0 = blockIdx.x * QB;
  const int kb = w * 128;
  const float* zp = z + (size_t)(n0 >> 12) * DDIM * TLEN + (n0 & (TLEN - 1));

  // ---- stage zf[d][q] (exact fp32), coalesced float4 ----
#pragma unroll
  for (int i = 0; i < 8; ++i) {
    int s4 = i * 512 + tid;            // 4096 float4 slots
    int d = s4 >> 4, q4 = (s4 & 15) * 4;
    *(float4*)&zf[d * QB + q4] = *(const float4*)(zp + (size_t)d * TLEN + q4);
  }
  __syncthreads();

  // ---- cooperative A-fragment build (hi only, once per block) ----
#pragma unroll
  for (int i = 0; i < 4; ++i) {
    int s = i * 512 + tid;             // 2048 slots: ks(8) x mt(4) x lane(64)
    int ks = s >> 8, mt = (s >> 6) & 3, ln = s & 63;
    int q = mt * 16 + (ln & 15);
    int d0 = ks * 32 + (ln >> 4) * 8;
    short8 h;
#pragma unroll
    for (int j = 0; j < 8; ++j) h[j] = (short)f2bf(zf[(d0 + j) * QB + q]);
    abh[s] = h;
  }
  __syncthreads();

  // ---- MFMA main loop (1 pass, 2-deep B prefetch) ----
  f32x4 acc[4][8];
#pragma unroll
  for (int mt = 0; mt < 4; ++mt)
#pragma unroll
    for (int nt = 0; nt < 8; ++nt) {
      f32x4 zz = {0.f, 0.f, 0.f, 0.f};
      acc[mt][nt] = zz;
    }

  const short* ebp = ebh + (size_t)(kb + c) * DDIM + g * 8;
  // linear tile index m = ks*8+nt; offset(m) = (m&7)*16*DDIM + (m>>3)*32
  short8 pb0 = *(const short8*)(ebp);                 // m=0
  short8 pb1 = *(const short8*)(ebp + 16 * DDIM);     // m=1

  for (int ks = 0; ks < 8; ++ks) {
    short8 ah[4];
#pragma unroll
    for (int mt = 0; mt < 4; ++mt) ah[mt] = abh[ks * 256 + mt * 64 + lane];
#pragma unroll
    for (int nt = 0; nt < 8; ++nt) {
      short8 bh = (nt & 1) ? pb1 : pb0;
      int m = (ks * 8 + nt + 2) & 63;   // branch-free wraparound prefetch
      size_t off = (size_t)(m & 7) * (16 * DDIM) + (size_t)(m >> 3) * 32;
      short8 nv = *(const short8*)(ebp + off);
      if (nt & 1) pb1 = nv; else pb0 = nv;
#pragma unroll
      for (int mt = 0; mt < 4; ++mt)
        acc[mt][nt] =
            __builtin_amdgcn_mfma_f32_16x16x32_bf16(ah[mt], bh, acc[mt][nt], 0, 0, 0);
    }
  }
  __syncthreads();  // abh reads done; alias region becomes writable

  // ---- z2 (exact pairwise) + sabs (bound input) + epilogue init ----
  if (tid < QB) {
    z2s[tid] = np_sumsq_256(&zf[tid], QB);
    float sa = 0.f;
    for (int d = 0; d < DDIM; ++d) sa += fabsf(zf[d * QB + tid]);
    sabs[tid] = sa;
    cnt[tid] = 0;
    ovf[tid] = 0;
  }

  const float maxe = __uint_as_float(*maxeU);

  float e2c[8];
#pragma unroll
  for (int nt = 0; nt < 8; ++nt) e2c[nt] = e2[kb + nt * 16 + c];

  float smin[4][4];
#pragma unroll
  for (int mt = 0; mt < 4; ++mt)
#pragma unroll
    for (int r = 0; r < 4; ++r) {
      float m = FLT_MAX_C;
#pragma unroll
      for (int nt = 0; nt < 8; ++nt)
        m = fminf(m, e2c[nt] - 2.0f * acc[mt][nt][r]);
      smin[mt][r] = m;
    }
#pragma unroll
  for (int mt = 0; mt < 4; ++mt)
#pragma unroll
    for (int r = 0; r < 4; ++r) {
#pragma unroll
      for (int m = 1; m < 16; m <<= 1)
        smin[mt][r] = fminf(smin[mt][r], __shfl_xor(smin[mt][r], m, 64));
    }
  if (c == 0) {
#pragma unroll
    for (int mt = 0; mt < 4; ++mt)
#pragma unroll
      for (int r = 0; r < 4; ++r)
        sm[w * QB + mt * 16 + g * 4 + r] = smin[mt][r];
  }
  __syncthreads();
  if (tid < QB) {
    float m = sm[tid];
#pragma unroll
    for (int wv = 1; wv < 8; ++wv) m = fminf(m, sm[wv * QB + tid]);
    qmin[tid] = m;
  }
  __syncthreads();

  // ---- candidate collection (per-query rigorous window) ----
#pragma unroll
  for (int mt = 0; mt < 4; ++mt)
#pragma unroll
    for (int r = 0; r < 4; ++r) {
      const int ql = mt * 16 + g * 4 + r;
      const float lim = qmin[ql] + (maxe * sabs[ql]) * 0.009f + 2e-4f;
#pragma unroll
      for (int nt = 0; nt < 8; ++nt) {
        float s = e2c[nt] - 2.0f * acc[mt][nt][r];
        if (s <= lim) {
          int p = atomicAdd(&cnt[ql], 1);
          if (p < MAXC) cand[ql * MAXC + p] = kb + nt * 16 + c;
          else ovf[ql] = 1;
        }
      }
    }
  __syncthreads();

  // ---- exact recheck (reference fp32 chain; z from LDS), 8 slots/query ----
  {
    const int q = tid & 63;
    const int slot = tid >> 6;
    const float z2q = z2s[q];
    float bestd = FLT_MAX_C;
    int besti = (1 << 30);
    const bool all = (ovf[q] != 0) || (cnt[q] > MAXC);
    const int count = all ? KCODES : cnt[q];
    for (int ci = slot; ci < count; ci += 8) {
      const int k = all ? ci : cand[q * MAXC + ci];
      const float4* ek = (const float4*)(emb + (size_t)k * DDIM);
      float a0 = 0.f;
      for (int dd = 0; dd < 64; ++dd) {
        float4 e4 = ek[dd];
        a0 = __fmaf_rn(zf[(dd * 4 + 0) * QB + q], e4.x, a0);
        a0 = __fmaf_rn(zf[(dd * 4 + 1) * QB + q], e4.y, a0);
        a0 = __fmaf_rn(zf[(dd * 4 + 2) * QB + q], e4.z, a0);
        a0 = __fmaf_rn(zf[(dd * 4 + 3) * QB + q], e4.w, a0);
      }
      float dist = __fsub_rn(__fadd_rn(z2q, e2[k]), __fmul_rn(2.0f, a0));
      if (dist < bestd || (dist == bestd && k < besti)) { bestd = dist; besti = k; }
    }
    bd[q * 8 + slot] = bestd;
    bk[q * 8 + slot] = besti;
  }
  __syncthreads();

  if (tid < QB) {
    float B = bd[tid * 8 + 0];
    int K = bk[tid * 8 + 0];
#pragma unroll
    for (int s = 1; s < 8; ++s) {
      float d2 = bd[tid * 8 + s];
      int k2 = bk[tid * 8 + s];
      if (d2 < B || (d2 == B && k2 < K)) { B = d2; K = k2; }
    }
    idx[n0 + tid] = K;
    atomicAdd(&hist[K], 1);
    double ls = (double)B;
#pragma unroll
    for (int m = 1; m < 64; m <<= 1) ls += __shfl_xor(ls, m, 64);
    if (tid == 0) lossp[blockIdx.x] = ls;
  }
}

// ---------------------------------------------------------------------------
// k_idxout: indices as FLOAT32
// ---------------------------------------------------------------------------
__global__ void k_idxout(const int* __restrict__ idx,
                         float* __restrict__ oidx) {
  int n = blockIdx.x * 256 + threadIdx.x;
  oidx[n] = (float)(idx[n] & (KCODES - 1));
}

// ---------------------------------------------------------------------------
// k_gather: out[b,d,t] = emb[idx[b,t], d]; one block per (b,d)
// ---------------------------------------------------------------------------
__global__ void k_gather(const float* __restrict__ embT,
                         const int* __restrict__ idx,
                         float* __restrict__ out) {
  __shared__ float er[KCODES];
  const int blk = blockIdx.x;  // b*D + d
  const int bq = blk >> 8;
  const int d = blk & 255;
  const int tid = threadIdx.x;
  *((float4*)&er[tid * 4]) =
      *((const float4*)(embT + (size_t)d * KCODES + tid * 4));
  __syncthreads();
  const int* ip = idx + (size_t)bq * TLEN;
  float* op = out + (size_t)blk * TLEN;
#pragma unroll
  for (int c = 0; c < 16; ++c) {
    int t = c * 256 + tid;
    int kk = ip[t] & (KCODES - 1);
    op[t] = er[kk];
  }
}

// ---------------------------------------------------------------------------
// k_final: loss and perplexity (deterministic fixed-tree reductions)
// lossp: 1024 per-block partials.
// ---------------------------------------------------------------------------
__global__ void k_final(const int* __restrict__ hist,
                        const double* __restrict__ lossp,
                        float* __restrict__ out2) {
  const int tid = threadIdx.x;  // 256
  double ls = 0.0;
  for (int i = 0; i < 4; ++i) ls += lossp[tid * 4 + i];
  float es = 0.f;
  for (int i = tid; i < KCODES; i += 256) {
    float p = (float)hist[i] / 65536.0f;
    es += p * logf(p + 1e-10f);
  }
#pragma unroll
  for (int m = 1; m < 64; m <<= 1) {
    ls += __shfl_xor(ls, m, 64);
    es += __shfl_xor(es, m, 64);
  }
  __shared__ double lw[4];
  __shared__ float ew[4];
  if ((tid & 63) == 0) { lw[tid >> 6] = ls; ew[tid >> 6] = es; }
  __syncthreads();
  if (tid == 0) {
    double lt = lw[0] + lw[1] + lw[2] + lw[3];
    float et = ew[0] + ew[1] + ew[2] + ew[3];
    float loss = 0.25f * (float)(lt / (double)((long long)NQ * DDIM));
    float perp = expf(-et);
    out2[0] = loss;
    out2[1] = perp;
  }
}

// ---------------------------------------------------------------------------
// workspace layout (bytes):
//   embT  : 0        .. 1048576   (D*K floats)
//   e2    : 1048576  .. 1052672   (K floats)
//   idx   : 1052672  .. 1314816   (N ints)
//   hist  : 1314816  .. 1318912   (K ints)        <- memset each launch
//   maxe  : 1318912  .. 1318916   (1 uint)        <- memset with hist
//   lossp : 1318920  .. 1327112   (1024 doubles)  <- fully written
//   ebh   : 1327120  .. 1851408   (K*D bf16 hi)
// total ~1.85 MB (<= round-8's proven 2.38 MB footprint)
// ---------------------------------------------------------------------------
extern "C" void kernel_launch(void* const* d_in, const int* in_sizes, int n_in,
                              void* d_out, int out_size, void* d_ws, size_t ws_size,
                              hipStream_t stream) {
  const float* z = (const float*)d_in[0];
  const float* emb = (const float*)d_in[1];
  float* out = (float*)d_out;

  char* ws = (char*)d_ws;
  float* embT = (float*)(ws);
  float* e2 = (float*)(ws + 1048576);
  int* idx = (int*)(ws + 1052672);
  int* hist = (int*)(ws + 1314816);
  unsigned* maxe = (unsigned*)(ws + 1318912);
  double* lossp = (double*)(ws + 1318920);
  short* ebh = (short*)(ws + 1327120);

  float* oidx = out + ((size_t)out_size - 2 - NQ);
  float* out2 = out + ((size_t)out_size - 2);

  // allow 96KB dynamic LDS for k_mdist
  (void)hipFuncSetAttribute((const void*)k_mdist,
                            hipFuncAttributeMaxDynamicSharedMemorySize,
                            98304);

  hipMemsetAsync(hist, 0, KCODES * sizeof(int) + sizeof(unsigned), stream);

  k_prep<<<KCODES, 256, 0, stream>>>(emb, embT, e2, ebh, maxe);
  k_mdist<<<NQ / QB, 512, 98304, stream>>>(z, emb, ebh, e2, maxe, idx, hist,
                                           lossp);
  k_idxout<<<NQ / 256, 256, 0, stream>>>(idx, oidx);
  k_gather<<<BB * DDIM, 256, 0, stream>>>(embT, idx, out);
  k_final<<<1, 256, 0, stream>>>(hist, lossp, out2);
}